// Round 7
// baseline (405.070 us; speedup 1.0000x reference)
//
#include <hip/hip_runtime.h>
#include <hip/hip_bf16.h>
#include <stdint.h>

#define SEQ 2048
#define HDIM 128
#define NHEADS 32
#define NKVH 4

typedef unsigned short u16;
typedef __bf16 bf16_t;
typedef bf16_t bf16x8 __attribute__((ext_vector_type(8)));
typedef float floatx4 __attribute__((ext_vector_type(4)));

__device__ __forceinline__ float bf2f(u16 u) {
  union { uint32_t i; float f; } v; v.i = ((uint32_t)u) << 16; return v.f;
}
__device__ __forceinline__ u16 f2bf(float f) {
  if (__builtin_isnan(f)) return 0;
  union { float f; uint32_t i; } v; v.f = f;
  uint32_t r = v.i + 0x7fffu + ((v.i >> 16) & 1u);
  return (u16)(r >> 16);
}
__device__ __forceinline__ float loadf_any(const void* p, size_t i, int isbf) {
  return isbf ? bf2f(((const u16*)p)[i]) : ((const float*)p)[i];
}

__device__ __forceinline__ void gload_lds16(const u16* g, u16* l) {
  __builtin_amdgcn_global_load_lds((__attribute__((address_space(1))) void*)g,
                                   (__attribute__((address_space(3))) void*)l,
                                   16, 0, 0);
}

__device__ __forceinline__ floatx4 mfma16(bf16x8 a, bf16x8 b, floatx4 c) {
  return __builtin_amdgcn_mfma_f32_16x16x32_bf16(a, b, c, 0, 0, 0);
}

// ---------------------------------------------------------------------------
// Fused per-tensor dtype detection: one launch, one block per input.
// flag=1 if bf16, 0 if fp32. Block 0 also sets flags[15]=1 (constant).
// ---------------------------------------------------------------------------
struct InPack { const u16* p[9]; int n[9]; };

__global__ void detect_all(InPack pk, int* __restrict__ flags) {
  const int which = blockIdx.x;
  const u16* x = pk.p[which];
  const int n = pk.n[which];
  __shared__ int s_sane, s_zeven, s_zodd;
  if (threadIdx.x == 0) { s_sane = 0; s_zeven = 0; s_zodd = 0; }
  __syncthreads();
  const int ns = n < 8192 ? n : 8192;
  int sane = 0, zeven = 0, zodd = 0;
  for (int i = threadIdx.x; i < ns; i += 256) {
    const u16 u = x[i];
    const int e = (u >> 7) & 0xff;
    if ((e >= 96 && e <= 159) || u == 0) sane++;
    if (u == 0) { if (i & 1) zodd++; else zeven++; }
  }
#pragma unroll
  for (int off = 32; off >= 1; off >>= 1) {
    sane += __shfl_xor(sane, off, 64);
    zeven += __shfl_xor(zeven, off, 64);
    zodd += __shfl_xor(zodd, off, 64);
  }
  if ((threadIdx.x & 63) == 0) {
    atomicAdd(&s_sane, sane);
    atomicAdd(&s_zeven, zeven);
    atomicAdd(&s_zodd, zodd);
  }
  __syncthreads();
  if (threadIdx.x == 0) {
    const int even = (ns + 1) / 2, odd = ns / 2;
    const bool mostly_sane = (s_sane * 10 >= ns * 9);
    const bool fp32_const_pattern = (s_zeven * 2 >= even) && (s_zodd * 10 <= odd);
    flags[which] = (mostly_sane && !fp32_const_pattern) ? 1 : 0;
    if (which == 0) flags[15] = 1;
  }
}

// ---------------------------------------------------------------------------
// Transpose tile helper: in (R x C, fp32|bf16) -> out (C x R, bf16).
// ---------------------------------------------------------------------------
__device__ __forceinline__ void transpose_tile(
    u16 (&tile)[64][65], const void* __restrict__ in, u16* __restrict__ out,
    int R, int C, int isbf, int bx, int by) {
  const int c0 = bx * 64, r0 = by * 64;
  const int t = threadIdx.x;
#pragma unroll
  for (int i = 0; i < 16; i++) {
    const int idx = i * 256 + t;
    const int r = idx >> 6, c = idx & 63;
    tile[r][c] = (u16)(isbf ? ((const u16*)in)[(size_t)(r0 + r) * C + c0 + c]
                            : f2bf(((const float*)in)[(size_t)(r0 + r) * C + c0 + c]));
  }
  __syncthreads();
#pragma unroll
  for (int i = 0; i < 16; i++) {
    const int idx = i * 256 + t;
    const int cc = idx >> 6, rr = idx & 63;
    out[(size_t)(c0 + cc) * R + r0 + rr] = tile[rr][cc];
  }
}

// ---------------------------------------------------------------------------
// Fused prep: ONE launch for {hidden convert, wq^T, wk^T, wv^T}.
// ---------------------------------------------------------------------------
__global__ __launch_bounds__(256) void prep_all(
    const void* __restrict__ hs, const void* __restrict__ wq,
    const void* __restrict__ wk, const void* __restrict__ wv,
    u16* __restrict__ Hb, u16* __restrict__ wqkvT,
    const int* __restrict__ flags) {
  __shared__ u16 tile[64][65];
  const int b = blockIdx.x;
  if (b < 2048) {
    transpose_tile(tile, wq, wqkvT, 2048, 4096, flags[1], b & 63, b >> 6);
  } else if (b < 2304) {
    const int r = b - 2048;
    transpose_tile(tile, wk, wqkvT + 4096ull * 2048, 2048, 512, flags[2],
                   r & 7, r >> 3);
  } else if (b < 2560) {
    const int r = b - 2304;
    transpose_tile(tile, wv, wqkvT + 4608ull * 2048, 2048, 512, flags[3],
                   r & 7, r >> 3);
  } else {
    const int r = b - 2560;
    const int isbf = flags[0];
#pragma unroll
    for (int i = 0; i < 4; i++) {
      const int idx = (r * 4 + i) * 256 + threadIdx.x;
      Hb[idx] = isbf ? ((const u16*)hs)[idx] : f2bf(((const float*)hs)[idx]);
    }
  }
}

// ---------------------------------------------------------------------------
// dtype-aware transpose: standalone launch kept for wo (runs after flash).
// ---------------------------------------------------------------------------
__global__ __launch_bounds__(256) void transpose_any(
    const void* __restrict__ in, u16* __restrict__ out, int R, int C,
    const int* __restrict__ flag) {
  __shared__ u16 tile[64][65];
  transpose_tile(tile, in, out, R, C, *flag, blockIdx.x, blockIdx.y);
}

// ---------------------------------------------------------------------------
// m97-structure GEMM (128x128 tile): QKV projection (640 blocks = 2.5/CU).
// ---------------------------------------------------------------------------
__global__ __launch_bounds__(256) void gemm_bt_bf16(
    const u16* __restrict__ A, const u16* __restrict__ BT,
    void* __restrict__ C, int M, int N, int K,
    const int* __restrict__ cflag) {
  __shared__ alignas(16) u16 As[128 * 32];
  __shared__ alignas(16) u16 Bs[128 * 32];
  const int t = threadIdx.x;
  const int w = t >> 6;
  const int lane = t & 63;
  const int lhi = lane >> 4, llo = lane & 15;
  const int m0 = blockIdx.y * 128, n0 = blockIdx.x * 128;
  const int wm = (w & 1) * 64, wn = (w >> 1) * 64;

  floatx4 acc[4][4];
#pragma unroll
  for (int i = 0; i < 4; i++)
#pragma unroll
    for (int j = 0; j < 4; j++) acc[i][j] = (floatx4)(0.0f);

  for (int k0 = 0; k0 < K; k0 += 32) {
#pragma unroll
    for (int r = 0; r < 2; r++) {
      const int c = r * 256 + t;
      const int row = c >> 2, kc = c & 3;
      const int base = (r * 256 + w * 64) * 8;
      gload_lds16(A + (size_t)(m0 + row) * K + k0 + kc * 8, &As[base]);
      gload_lds16(BT + (size_t)(n0 + row) * K + k0 + kc * 8, &Bs[base]);
    }
    __syncthreads();
    bf16x8 af[4], bfr[4];
#pragma unroll
    for (int i = 0; i < 4; i++)
      af[i] = *(const bf16x8*)&As[(wm + i * 16 + llo) * 32 + lhi * 8];
#pragma unroll
    for (int j = 0; j < 4; j++)
      bfr[j] = *(const bf16x8*)&Bs[(wn + j * 16 + llo) * 32 + lhi * 8];
#pragma unroll
    for (int i = 0; i < 4; i++)
#pragma unroll
      for (int j = 0; j < 4; j++)
        acc[i][j] = mfma16(af[i], bfr[j], acc[i][j]);
    __syncthreads();
  }
  const int cbf = *cflag;
#pragma unroll
  for (int i = 0; i < 4; i++) {
    const int row0 = m0 + wm + i * 16 + lhi * 4;
#pragma unroll
    for (int j = 0; j < 4; j++) {
      const int col = n0 + wn + j * 16 + llo;
#pragma unroll
      for (int r = 0; r < 4; r++) {
        if (cbf) ((u16*)C)[(size_t)(row0 + r) * N + col] = f2bf(acc[i][j][r]);
        else ((float*)C)[(size_t)(row0 + r) * N + col] = acc[i][j][r];
      }
    }
  }
}

// ---------------------------------------------------------------------------
// Within-block split-K GEMM for small output grids (output projection).
// ---------------------------------------------------------------------------
__global__ __launch_bounds__(1024) void gemm_bt_splitk(
    const u16* __restrict__ A, const u16* __restrict__ BT,
    void* __restrict__ C, int M, int N, int K,
    const int* __restrict__ cflag) {
  __shared__ alignas(16) u16 smem[4][2][128 * 32];  // 64 KiB total
  const int t = threadIdx.x;
  const int g = t >> 8;        // k-group 0..3
  const int tg = t & 255;      // thread within group
  const int w = tg >> 6;       // wave within group 0..3
  const int lane = t & 63;
  const int lhi = lane >> 4, llo = lane & 15;
  const int m0 = blockIdx.y * 128, n0 = blockIdx.x * 128;
  const int wm = (w & 1) * 64, wn = (w >> 1) * 64;
  const int kq = K >> 2;
  const int kbeg = g * kq;
  u16* As = smem[g][0];
  u16* Bs = smem[g][1];

  floatx4 acc[4][4];
#pragma unroll
  for (int i = 0; i < 4; i++)
#pragma unroll
    for (int j = 0; j < 4; j++) acc[i][j] = (floatx4)(0.0f);

  for (int k0 = 0; k0 < kq; k0 += 32) {
#pragma unroll
    for (int r = 0; r < 2; r++) {
      const int c = r * 256 + tg;
      const int row = c >> 2, kc = c & 3;
      const int base = (r * 256 + w * 64) * 8;  // wave-uniform LDS dest
      gload_lds16(A + (size_t)(m0 + row) * K + kbeg + k0 + kc * 8, &As[base]);
      gload_lds16(BT + (size_t)(n0 + row) * K + kbeg + k0 + kc * 8, &Bs[base]);
    }
    __syncthreads();
    bf16x8 af[4], bfr[4];
#pragma unroll
    for (int i = 0; i < 4; i++)
      af[i] = *(const bf16x8*)&As[(wm + i * 16 + llo) * 32 + lhi * 8];
#pragma unroll
    for (int j = 0; j < 4; j++)
      bfr[j] = *(const bf16x8*)&Bs[(wn + j * 16 + llo) * 32 + lhi * 8];
#pragma unroll
    for (int i = 0; i < 4; i++)
#pragma unroll
      for (int j = 0; j < 4; j++)
        acc[i][j] = mfma16(af[i], bfr[j], acc[i][j]);
    __syncthreads();
  }

  // cross-group reduce: reuse staging LDS as 128x128 f32 (exactly 64 KiB).
  float* red = (float*)&smem[0][0][0];
  for (int gg = 0; gg < 4; gg++) {
    if (g == gg) {
#pragma unroll
      for (int i = 0; i < 4; i++)
#pragma unroll
        for (int j = 0; j < 4; j++) {
          const int col = wn + j * 16 + llo;
#pragma unroll
          for (int r = 0; r < 4; r++) {
            const int row = wm + i * 16 + lhi * 4 + r;
            if (gg == 0) red[row * 128 + col] = acc[i][j][r];
            else red[row * 128 + col] += acc[i][j][r];
          }
        }
    }
    __syncthreads();
  }
  const int cbf = *cflag;
#pragma unroll
  for (int i = 0; i < 16; i++) {
    const int idx = i * 1024 + t;           // 16384 = 128*128
    const int rr = idx >> 7, cc = idx & 127;
    const float v = red[rr * 128 + cc];
    if (cbf) ((u16*)C)[(size_t)(m0 + rr) * N + n0 + cc] = f2bf(v);
    else ((float*)C)[(size_t)(m0 + rr) * N + n0 + cc] = v;
  }
}

// ---------------------------------------------------------------------------
// RMSNorm + RoPE in place on fused QKV projection (S x 5120).
// ---------------------------------------------------------------------------
__global__ __launch_bounds__(128) void norm_rope_inplace(
    u16* __restrict__ QKV,
    const void* __restrict__ qw, const void* __restrict__ kw,
    const void* __restrict__ cosb, const void* __restrict__ sinb,
    const int* __restrict__ flags) {
  const int qwbf = flags[5], kwbf = flags[6], cbf = flags[7], sbf = flags[8];
  const int s = blockIdx.x, hy = blockIdx.y, d = threadIdx.x;
  const bool isQ = hy < NHEADS;
  const int col = isQ ? hy * HDIM : 4096 + (hy - NHEADS) * HDIM;
  u16* ptr = QKV + (size_t)s * 5120 + col + d;
  const float x = bf2f(*ptr);
  float v = x * x;
#pragma unroll
  for (int off = 32; off >= 1; off >>= 1) v += __shfl_xor(v, off, 64);
  __shared__ float sw[2];
  __shared__ float sh[128];
  if ((d & 63) == 0) sw[d >> 6] = v;
  __syncthreads();
  const float mean = (sw[0] + sw[1]) * (1.0f / 128.0f);
  const float rn = rsqrtf(mean + 1e-6f);
  const float wv = isQ ? loadf_any(qw, d, qwbf) : loadf_any(kw, d, kwbf);
  const float xn = x * rn * wv;
  sh[d] = xn;
  __syncthreads();
  const float other = sh[d ^ 64];
  const float cv = loadf_any(cosb, (size_t)s * HDIM + d, cbf);
  const float sv = loadf_any(sinb, (size_t)s * HDIM + d, sbf);
  const float o = xn * cv + (d < 64 ? -other : other) * sv;
  *ptr = f2bf(o);
}

// ---------------------------------------------------------------------------
// V transpose: QKV cols 4608..5119 (S x 512, bf16) -> Vt (NKV, HD, S).
// ---------------------------------------------------------------------------
__global__ __launch_bounds__(256) void v_transpose(
    const u16* __restrict__ QKV, u16* __restrict__ Vt) {
  __shared__ u16 tile[64][65];
  const int s0 = blockIdx.x * 64, d0 = blockIdx.y * 64, hk = blockIdx.z;
  const int t = threadIdx.x;
#pragma unroll
  for (int i = 0; i < 16; i++) {
    const int idx = i * 256 + t;
    const int r = idx >> 6, c = idx & 63;
    tile[r][c] = QKV[(size_t)(s0 + r) * 5120 + 4608 + hk * HDIM + d0 + c];
  }
  __syncthreads();
#pragma unroll
  for (int i = 0; i < 16; i++) {
    const int idx = i * 256 + t;
    const int dd = idx >> 6, ss = idx & 63;
    Vt[((size_t)hk * HDIM + d0 + dd) * SEQ + s0 + ss] = tile[ss][dd];
  }
}

// ---------------------------------------------------------------------------
// Flash attention v3: double-buffered K/V with STATICALLY DISTINCT LDS
// arrays (KldsA/KldsB, VldsA/VldsB) + 2x-unrolled loop (ntiles=2qt+2 always
// even) so SIInsertWaitcnts can prove the ds_reads don't alias the
// outstanding global_load_lds DMA and skip the conservative vmcnt(0) drain
// (suspected cause of the round-2/3 regression). One barrier per half-iter;
// prefetch issued right after the barrier -> drained a full iteration later.
// Mid-softmax fence is lgkmcnt(0)-ONLY + sched_barrier(0) (rule #18) — the
// round-3 bug was waitcnt(0) draining vmcnt there. Half-split P buffer
// (stride 40) keeps LDS at 64K + 10K = 75776 B -> 2 blocks/CU (grid = 2/CU).
// ---------------------------------------------------------------------------
__device__ __forceinline__ void fa_stage(
    const u16* __restrict__ QKV, const u16* __restrict__ Vt,
    u16* __restrict__ Kdst, u16* __restrict__ Vdst,
    int kv0, int hk, int t, int w) {
#pragma unroll
  for (int r = 0; r < 4; r++) {
    const int c = r * 256 + t;
    const int base = (r * 256 + w * 64) * 8;
    // K chunk (row=c>>4, s=c&15) holds global chunk s^(row&7)
    gload_lds16(QKV + (size_t)(kv0 + (c >> 4)) * 5120 + 4096 + hk * HDIM +
                    (((c & 15) ^ ((c >> 4) & 7)) * 8),
                &Kdst[base]);
    // V chunk (row=c>>3, s=c&7) holds global chunk s^(row&7)
    gload_lds16(Vt + ((size_t)hk * HDIM + (c >> 3)) * SEQ + kv0 +
                    (((c & 7) ^ ((c >> 3) & 7)) * 8),
                &Vdst[base]);
  }
}

__device__ __forceinline__ void fa_compute(
    const u16* __restrict__ Kb, const u16* __restrict__ Vb,
    u16* __restrict__ Pw, const bf16x8 (&qf)[2][4],
    floatx4 (&oacc)[2][8], float (&lacc)[2][4],
    int kv0, int q0, int qw0, int lhi, int llo) {
  const float scale = 0.08838834764831845f;  // 1/sqrt(128)
  const float SMAX = 16.0f;                  // static softmax reference
  floatx4 sacc[2][4];
#pragma unroll
  for (int i = 0; i < 2; i++)
#pragma unroll
    for (int j = 0; j < 4; j++) sacc[i][j] = (floatx4)(0.0f);
#pragma unroll
  for (int j = 0; j < 4; j++) {
#pragma unroll
    for (int c = 0; c < 4; c++) {
      bf16x8 kf = *(const bf16x8*)&Kb[(j * 16 + llo) * 128 +
                                      (((c * 4 + lhi) ^ (llo & 7)) * 8)];
      sacc[0][j] = mfma16(qf[0][c], kf, sacc[0][j]);
      sacc[1][j] = mfma16(qf[1][c], kf, sacc[1][j]);
    }
  }
  if (kv0 + 64 > q0) {
#pragma unroll
    for (int i = 0; i < 2; i++)
#pragma unroll
      for (int j = 0; j < 4; j++) {
        const int n = kv0 + j * 16 + llo;
#pragma unroll
        for (int r = 0; r < 4; r++) {
          const int mm = qw0 + i * 16 + lhi * 4 + r;
          if (n > mm) sacc[i][j][r] = -30000.0f;
        }
      }
  }
  // two kv-32 halves sharing the wave-private P buffer (stride 40):
#pragma unroll
  for (int hh = 0; hh < 2; hh++) {
#pragma unroll
    for (int i = 0; i < 2; i++)
#pragma unroll
      for (int jj = 0; jj < 2; jj++) {
        const int j = hh * 2 + jj;
#pragma unroll
        for (int r = 0; r < 4; r++) {
          const float p = __expf(fmaf(sacc[i][j][r], scale, -SMAX));
          lacc[i][r] += p;
          *(bf16_t*)&Pw[(i * 16 + lhi * 4 + r) * 40 + jj * 16 + llo] =
              (bf16_t)p;
        }
      }
    // Pw is wave-private: lgkm-ONLY drain (vmcnt prefetch stays in flight!)
    asm volatile("s_waitcnt lgkmcnt(0)" ::: "memory");
    __builtin_amdgcn_sched_barrier(0);
    bf16x8 pf0 = *(const bf16x8*)&Pw[llo * 40 + lhi * 8];
    bf16x8 pf1 = *(const bf16x8*)&Pw[(16 + llo) * 40 + lhi * 8];
#pragma unroll
    for (int d = 0; d < 8; d++) {
      bf16x8 vf = *(const bf16x8*)&Vb[(d * 16 + llo) * 64 +
                                      (((hh * 4 + lhi) ^ (llo & 7)) * 8)];
      oacc[0][d] = mfma16(pf0, vf, oacc[0][d]);
      oacc[1][d] = mfma16(pf1, vf, oacc[1][d]);
    }
  }
}

__global__ __launch_bounds__(256) void flash_attn(
    const u16* __restrict__ QKV, const u16* __restrict__ Vt,
    u16* __restrict__ O) {
  __shared__ alignas(16) u16 KldsA[64 * 128];   // statically distinct buffers
  __shared__ alignas(16) u16 KldsB[64 * 128];   //   (alias-analysis-friendly)
  __shared__ alignas(16) u16 VldsA[128 * 64];
  __shared__ alignas(16) u16 VldsB[128 * 64];
  __shared__ alignas(16) u16 Plds[4][32 * 40];  // per-wave P half, stride 40
  const int t = threadIdx.x;
  const int w = t >> 6;
  const int lane = t & 63;
  const int lhi = lane >> 4, llo = lane & 15;
  const int b = blockIdx.x;
  const int bi = b & 255;
  const int qt = (b < 256) ? (15 - (bi >> 5)) : (bi >> 5);  // paired balance
  const int h = bi & 31, hk = h >> 3;
  const int q0 = qt * 128;
  const int qw0 = q0 + w * 32;

  bf16x8 qf[2][4];
#pragma unroll
  for (int i = 0; i < 2; i++)
#pragma unroll
    for (int c = 0; c < 4; c++)
      qf[i][c] = *(const bf16x8*)(QKV + (size_t)(qw0 + i * 16 + llo) * 5120 +
                                  h * HDIM + c * 32 + lhi * 8);

  floatx4 oacc[2][8];
  float lacc[2][4];
#pragma unroll
  for (int i = 0; i < 2; i++) {
#pragma unroll
    for (int d = 0; d < 8; d++) oacc[i][d] = (floatx4)(0.0f);
#pragma unroll
    for (int r = 0; r < 4; r++) lacc[i][r] = 0.0f;
  }

  const int ntiles = 2 * qt + 2;  // always even
  fa_stage(QKV, Vt, KldsA, VldsA, 0, hk, t, w);
  for (int tt = 0; tt < ntiles; tt += 2) {
    // barrier: drains prev prefetch (a full iter old), publishes A, and
    // guarantees everyone is done reading B before we overwrite it.
    __syncthreads();
    fa_stage(QKV, Vt, KldsB, VldsB, (tt + 1) * 64, hk, t, w);
    fa_compute(KldsA, VldsA, &Plds[w][0], qf, oacc, lacc,
               tt * 64, q0, qw0, lhi, llo);
    __syncthreads();
    if (tt + 2 < ntiles)
      fa_stage(QKV, Vt, KldsA, VldsA, (tt + 2) * 64, hk, t, w);
    fa_compute(KldsB, VldsB, &Plds[w][0], qf, oacc, lacc,
               (tt + 1) * 64, q0, qw0, lhi, llo);
  }
  // epilogue: reduce l across the 16 llo lanes, normalize, store
#pragma unroll
  for (int i = 0; i < 2; i++)
#pragma unroll
    for (int r = 0; r < 4; r++) {
#pragma unroll
      for (int off = 1; off < 16; off <<= 1)
        lacc[i][r] += __shfl_xor(lacc[i][r], off, 64);
      const float linv = 1.0f / lacc[i][r];
      const int row = qw0 + i * 16 + lhi * 4 + r;
#pragma unroll
      for (int d = 0; d < 8; d++)
        O[(size_t)row * 4096 + h * HDIM + d * 16 + llo] =
            f2bf(oacc[i][d][r] * linv);
    }
}

// ---------------------------------------------------------------------------
extern "C" void kernel_launch(void* const* d_in, const int* in_sizes, int n_in,
                              void* d_out, int out_size, void* d_ws, size_t ws_size,
                              hipStream_t stream) {
  // Arena: 42 MB + flags (proven size). Overlays sequential-stream safe.
  char* ws = (char*)d_ws;
  u16* wqkvT  = (u16*)(ws);                   // 20 MB (5120,2048); attnO later
  u16* QKVp   = (u16*)(ws + (20ull << 20));   // 20 MB (S,5120); woT later
  u16* Vt     = (u16*)(ws + (40ull << 20));   //  2 MB (NKV,HD,S)
  int* flags  = (int*)(ws + (42ull << 20));   // 16 ints
  u16* attnO  = wqkvT;   // 16 MB, overlays wqkvT (dead after QKV GEMM)
  u16* woT    = QKVp;    // 16 MB, overlays QKVp (dead after flash)
  u16* Hb     = (u16*)d_out;  // 8 MB bf16 hidden (dead before final GEMM)

  InPack pk;
  for (int i = 0; i < 9; i++) { pk.p[i] = (const u16*)d_in[i]; pk.n[i] = in_sizes[i]; }
  detect_all<<<9, 256, 0, stream>>>(pk, flags);

  // Fused prep: convert + wq^T + wk^T + wv^T in ONE launch (was 4).
  prep_all<<<6656, 256, 0, stream>>>(
      d_in[0], d_in[1], d_in[2], d_in[3], Hb, wqkvT, flags);

  // Fused QKV projection: (S,2048) @ (2048,5120) -> (S,5120) bf16
  gemm_bt_bf16<<<dim3(40, 16), 256, 0, stream>>>(
      Hb, wqkvT, QKVp, 2048, 5120, 2048, flags + 15);

  norm_rope_inplace<<<dim3(2048, NHEADS + NKVH), 128, 0, stream>>>(
      QKVp, d_in[5], d_in[6], d_in[7], d_in[8], flags);
  v_transpose<<<dim3(32, 2, 4), 256, 0, stream>>>(QKVp, Vt);

  flash_attn<<<512, 256, 0, stream>>>(QKVp, Vt, attnO);

  transpose_any<<<dim3(32, 64), 256, 0, stream>>>(d_in[4], woT, 4096, 2048, flags + 4);
  // Output projection: within-block split-K=4 (2048x2048x4096)
  gemm_bt_splitk<<<dim3(16, 16), 1024, 0, stream>>>(
      attnO, woT, d_out, 2048, 2048, 4096, flags + 0);
}

// Round 8
// 385.818 us; speedup vs baseline: 1.0499x; 1.0499x over previous
//
#include <hip/hip_runtime.h>
#include <hip/hip_bf16.h>
#include <stdint.h>

#define SEQ 2048
#define HDIM 128
#define NHEADS 32
#define NKVH 4

typedef unsigned short u16;
typedef __bf16 bf16_t;
typedef bf16_t bf16x8 __attribute__((ext_vector_type(8)));
typedef float floatx4 __attribute__((ext_vector_type(4)));

__device__ __forceinline__ float bf2f(u16 u) {
  union { uint32_t i; float f; } v; v.i = ((uint32_t)u) << 16; return v.f;
}
__device__ __forceinline__ u16 f2bf(float f) {
  if (__builtin_isnan(f)) return 0;
  union { float f; uint32_t i; } v; v.f = f;
  uint32_t r = v.i + 0x7fffu + ((v.i >> 16) & 1u);
  return (u16)(r >> 16);
}
__device__ __forceinline__ float loadf_any(const void* p, size_t i, int isbf) {
  return isbf ? bf2f(((const u16*)p)[i]) : ((const float*)p)[i];
}

__device__ __forceinline__ void gload_lds16(const u16* g, u16* l) {
  __builtin_amdgcn_global_load_lds((__attribute__((address_space(1))) void*)g,
                                   (__attribute__((address_space(3))) void*)l,
                                   16, 0, 0);
}

__device__ __forceinline__ floatx4 mfma16(bf16x8 a, bf16x8 b, floatx4 c) {
  return __builtin_amdgcn_mfma_f32_16x16x32_bf16(a, b, c, 0, 0, 0);
}

// ---------------------------------------------------------------------------
// Fused per-tensor dtype detection: one launch, one block per input.
// flag=1 if bf16, 0 if fp32. Block 0 also sets flags[15]=1 (constant).
// ---------------------------------------------------------------------------
struct InPack { const u16* p[9]; int n[9]; };

__global__ void detect_all(InPack pk, int* __restrict__ flags) {
  const int which = blockIdx.x;
  const u16* x = pk.p[which];
  const int n = pk.n[which];
  __shared__ int s_sane, s_zeven, s_zodd;
  if (threadIdx.x == 0) { s_sane = 0; s_zeven = 0; s_zodd = 0; }
  __syncthreads();
  const int ns = n < 8192 ? n : 8192;
  int sane = 0, zeven = 0, zodd = 0;
  for (int i = threadIdx.x; i < ns; i += 256) {
    const u16 u = x[i];
    const int e = (u >> 7) & 0xff;
    if ((e >= 96 && e <= 159) || u == 0) sane++;
    if (u == 0) { if (i & 1) zodd++; else zeven++; }
  }
#pragma unroll
  for (int off = 32; off >= 1; off >>= 1) {
    sane += __shfl_xor(sane, off, 64);
    zeven += __shfl_xor(zeven, off, 64);
    zodd += __shfl_xor(zodd, off, 64);
  }
  if ((threadIdx.x & 63) == 0) {
    atomicAdd(&s_sane, sane);
    atomicAdd(&s_zeven, zeven);
    atomicAdd(&s_zodd, zodd);
  }
  __syncthreads();
  if (threadIdx.x == 0) {
    const int even = (ns + 1) / 2, odd = ns / 2;
    const bool mostly_sane = (s_sane * 10 >= ns * 9);
    const bool fp32_const_pattern = (s_zeven * 2 >= even) && (s_zodd * 10 <= odd);
    flags[which] = (mostly_sane && !fp32_const_pattern) ? 1 : 0;
    if (which == 0) flags[15] = 1;
  }
}

// ---------------------------------------------------------------------------
// Vectorized transpose tile: in (R x C, fp32|bf16) -> out (C x R, bf16).
// Global loads float4 (fp32) / ushort4 (bf16), global stores ushort4.
// LDS accesses stay scalar (pad-65 keeps them conflict-free; vector LDS
// would break 8B alignment on odd rows).
// ---------------------------------------------------------------------------
__device__ __forceinline__ void transpose_tile(
    u16 (&tile)[64][65], const void* __restrict__ in, u16* __restrict__ out,
    int R, int C, int isbf, int bx, int by) {
  const int c0 = bx * 64, r0 = by * 64;
  const int t = threadIdx.x;
  const int tr = t >> 4;         // 0..15
  const int tc4 = (t & 15) * 4;  // 0,4,..,60
  if (isbf) {
#pragma unroll
    for (int i = 0; i < 4; i++) {
      const int r = i * 16 + tr;
      const ushort4 v = *(const ushort4*)((const u16*)in +
                                          (size_t)(r0 + r) * C + c0 + tc4);
      tile[r][tc4 + 0] = v.x; tile[r][tc4 + 1] = v.y;
      tile[r][tc4 + 2] = v.z; tile[r][tc4 + 3] = v.w;
    }
  } else {
#pragma unroll
    for (int i = 0; i < 4; i++) {
      const int r = i * 16 + tr;
      const float4 v = *(const float4*)((const float*)in +
                                        (size_t)(r0 + r) * C + c0 + tc4);
      tile[r][tc4 + 0] = f2bf(v.x); tile[r][tc4 + 1] = f2bf(v.y);
      tile[r][tc4 + 2] = f2bf(v.z); tile[r][tc4 + 3] = f2bf(v.w);
    }
  }
  __syncthreads();
#pragma unroll
  for (int j = 0; j < 4; j++) {
    const int cc = j * 16 + tr;
    ushort4 o;
    o.x = tile[tc4 + 0][cc]; o.y = tile[tc4 + 1][cc];
    o.z = tile[tc4 + 2][cc]; o.w = tile[tc4 + 3][cc];
    *(ushort4*)(out + (size_t)(c0 + cc) * R + r0 + tc4) = o;
  }
}

// ---------------------------------------------------------------------------
// Fused prep: ONE launch for {hidden convert, wq^T, wk^T, wv^T}.
// Block ranges: [0,2048) wq | [2048,2304) wk | [2304,2560) wv |
//               [2560,6656) convert (4096 blocks x 1024 elems, vectorized).
// ---------------------------------------------------------------------------
__global__ __launch_bounds__(256) void prep_all(
    const void* __restrict__ hs, const void* __restrict__ wq,
    const void* __restrict__ wk, const void* __restrict__ wv,
    u16* __restrict__ Hb, u16* __restrict__ wqkvT,
    const int* __restrict__ flags) {
  __shared__ u16 tile[64][65];
  const int b = blockIdx.x;
  if (b < 2048) {
    transpose_tile(tile, wq, wqkvT, 2048, 4096, flags[1], b & 63, b >> 6);
  } else if (b < 2304) {
    const int r = b - 2048;
    transpose_tile(tile, wk, wqkvT + 4096ull * 2048, 2048, 512, flags[2],
                   r & 7, r >> 3);
  } else if (b < 2560) {
    const int r = b - 2304;
    transpose_tile(tile, wv, wqkvT + 4608ull * 2048, 2048, 512, flags[3],
                   r & 7, r >> 3);
  } else {
    const int r = b - 2560;
    const int base = r * 1024 + threadIdx.x * 4;
    if (flags[0]) {
      *(ushort4*)(Hb + base) = *(const ushort4*)((const u16*)hs + base);
    } else {
      const float4 v = *(const float4*)((const float*)hs + base);
      ushort4 o;
      o.x = f2bf(v.x); o.y = f2bf(v.y); o.z = f2bf(v.z); o.w = f2bf(v.w);
      *(ushort4*)(Hb + base) = o;
    }
  }
}

// ---------------------------------------------------------------------------
// dtype-aware transpose: standalone launch kept for wo (runs after flash).
// ---------------------------------------------------------------------------
__global__ __launch_bounds__(256) void transpose_any(
    const void* __restrict__ in, u16* __restrict__ out, int R, int C,
    const int* __restrict__ flag) {
  __shared__ u16 tile[64][65];
  transpose_tile(tile, in, out, R, C, *flag, blockIdx.x, blockIdx.y);
}

// ---------------------------------------------------------------------------
// m97-structure GEMM (128x128 tile): QKV projection (640 blocks = 2.5/CU).
// ---------------------------------------------------------------------------
__global__ __launch_bounds__(256) void gemm_bt_bf16(
    const u16* __restrict__ A, const u16* __restrict__ BT,
    void* __restrict__ C, int M, int N, int K,
    const int* __restrict__ cflag) {
  __shared__ alignas(16) u16 As[128 * 32];
  __shared__ alignas(16) u16 Bs[128 * 32];
  const int t = threadIdx.x;
  const int w = t >> 6;
  const int lane = t & 63;
  const int lhi = lane >> 4, llo = lane & 15;
  const int m0 = blockIdx.y * 128, n0 = blockIdx.x * 128;
  const int wm = (w & 1) * 64, wn = (w >> 1) * 64;

  floatx4 acc[4][4];
#pragma unroll
  for (int i = 0; i < 4; i++)
#pragma unroll
    for (int j = 0; j < 4; j++) acc[i][j] = (floatx4)(0.0f);

  for (int k0 = 0; k0 < K; k0 += 32) {
#pragma unroll
    for (int r = 0; r < 2; r++) {
      const int c = r * 256 + t;
      const int row = c >> 2, kc = c & 3;
      const int base = (r * 256 + w * 64) * 8;
      gload_lds16(A + (size_t)(m0 + row) * K + k0 + kc * 8, &As[base]);
      gload_lds16(BT + (size_t)(n0 + row) * K + k0 + kc * 8, &Bs[base]);
    }
    __syncthreads();
    bf16x8 af[4], bfr[4];
#pragma unroll
    for (int i = 0; i < 4; i++)
      af[i] = *(const bf16x8*)&As[(wm + i * 16 + llo) * 32 + lhi * 8];
#pragma unroll
    for (int j = 0; j < 4; j++)
      bfr[j] = *(const bf16x8*)&Bs[(wn + j * 16 + llo) * 32 + lhi * 8];
#pragma unroll
    for (int i = 0; i < 4; i++)
#pragma unroll
      for (int j = 0; j < 4; j++)
        acc[i][j] = mfma16(af[i], bfr[j], acc[i][j]);
    __syncthreads();
  }
  const int cbf = *cflag;
#pragma unroll
  for (int i = 0; i < 4; i++) {
    const int row0 = m0 + wm + i * 16 + lhi * 4;
#pragma unroll
    for (int j = 0; j < 4; j++) {
      const int col = n0 + wn + j * 16 + llo;
#pragma unroll
      for (int r = 0; r < 4; r++) {
        if (cbf) ((u16*)C)[(size_t)(row0 + r) * N + col] = f2bf(acc[i][j][r]);
        else ((float*)C)[(size_t)(row0 + r) * N + col] = acc[i][j][r];
      }
    }
  }
}

// ---------------------------------------------------------------------------
// Within-block split-K GEMM for small output grids (output projection).
// ---------------------------------------------------------------------------
__global__ __launch_bounds__(1024) void gemm_bt_splitk(
    const u16* __restrict__ A, const u16* __restrict__ BT,
    void* __restrict__ C, int M, int N, int K,
    const int* __restrict__ cflag) {
  __shared__ alignas(16) u16 smem[4][2][128 * 32];  // 64 KiB total
  const int t = threadIdx.x;
  const int g = t >> 8;        // k-group 0..3
  const int tg = t & 255;      // thread within group
  const int w = tg >> 6;       // wave within group 0..3
  const int lane = t & 63;
  const int lhi = lane >> 4, llo = lane & 15;
  const int m0 = blockIdx.y * 128, n0 = blockIdx.x * 128;
  const int wm = (w & 1) * 64, wn = (w >> 1) * 64;
  const int kq = K >> 2;
  const int kbeg = g * kq;
  u16* As = smem[g][0];
  u16* Bs = smem[g][1];

  floatx4 acc[4][4];
#pragma unroll
  for (int i = 0; i < 4; i++)
#pragma unroll
    for (int j = 0; j < 4; j++) acc[i][j] = (floatx4)(0.0f);

  for (int k0 = 0; k0 < kq; k0 += 32) {
#pragma unroll
    for (int r = 0; r < 2; r++) {
      const int c = r * 256 + tg;
      const int row = c >> 2, kc = c & 3;
      const int base = (r * 256 + w * 64) * 8;  // wave-uniform LDS dest
      gload_lds16(A + (size_t)(m0 + row) * K + kbeg + k0 + kc * 8, &As[base]);
      gload_lds16(BT + (size_t)(n0 + row) * K + kbeg + k0 + kc * 8, &Bs[base]);
    }
    __syncthreads();
    bf16x8 af[4], bfr[4];
#pragma unroll
    for (int i = 0; i < 4; i++)
      af[i] = *(const bf16x8*)&As[(wm + i * 16 + llo) * 32 + lhi * 8];
#pragma unroll
    for (int j = 0; j < 4; j++)
      bfr[j] = *(const bf16x8*)&Bs[(wn + j * 16 + llo) * 32 + lhi * 8];
#pragma unroll
    for (int i = 0; i < 4; i++)
#pragma unroll
      for (int j = 0; j < 4; j++)
        acc[i][j] = mfma16(af[i], bfr[j], acc[i][j]);
    __syncthreads();
  }

  // cross-group reduce: reuse staging LDS as 128x128 f32 (exactly 64 KiB).
  float* red = (float*)&smem[0][0][0];
  for (int gg = 0; gg < 4; gg++) {
    if (g == gg) {
#pragma unroll
      for (int i = 0; i < 4; i++)
#pragma unroll
        for (int j = 0; j < 4; j++) {
          const int col = wn + j * 16 + llo;
#pragma unroll
          for (int r = 0; r < 4; r++) {
            const int row = wm + i * 16 + lhi * 4 + r;
            if (gg == 0) red[row * 128 + col] = acc[i][j][r];
            else red[row * 128 + col] += acc[i][j][r];
          }
        }
    }
    __syncthreads();
  }
  const int cbf = *cflag;
#pragma unroll
  for (int i = 0; i < 16; i++) {
    const int idx = i * 1024 + t;           // 16384 = 128*128
    const int rr = idx >> 7, cc = idx & 127;
    const float v = red[rr * 128 + cc];
    if (cbf) ((u16*)C)[(size_t)(m0 + rr) * N + n0 + cc] = f2bf(v);
    else ((float*)C)[(size_t)(m0 + rr) * N + n0 + cc] = v;
  }
}

// ---------------------------------------------------------------------------
// Fused RMSNorm+RoPE (Q/K cols) + V transpose in ONE launch.
// Blocks [0,36864): norm, 256 threads = 2 heads of one s-row
//   (s = b/18, head pair = (b%18)*2 + t>>7, d = t&127).
// Blocks [36864,37120): V transpose, 256 blocks remapping the old
//   (32,2,4) grid; reads V cols (untouched by norm — independent).
// ---------------------------------------------------------------------------
__global__ __launch_bounds__(256) void norm_rope_vt(
    u16* __restrict__ QKV, u16* __restrict__ Vt,
    const void* __restrict__ qw, const void* __restrict__ kw,
    const void* __restrict__ cosb, const void* __restrict__ sinb,
    const int* __restrict__ flags) {
  __shared__ float sw[2][2];
  __shared__ float sh[2][128];
  __shared__ u16 tile[64][65];
  const int b = blockIdx.x;
  const int t = threadIdx.x;
  if (b < 36864) {
    const int qwbf = flags[5], kwbf = flags[6], cbf = flags[7], sbf = flags[8];
    const int s = b / 18, hp = b - s * 18;
    const int g = t >> 7, d = t & 127;
    const int hy = hp * 2 + g;
    const bool isQ = hy < NHEADS;
    const int col = isQ ? hy * HDIM : 4096 + (hy - NHEADS) * HDIM;
    u16* ptr = QKV + (size_t)s * 5120 + col + d;
    const float x = bf2f(*ptr);
    float v = x * x;
#pragma unroll
    for (int off = 32; off >= 1; off >>= 1) v += __shfl_xor(v, off, 64);
    if ((d & 63) == 0) sw[g][d >> 6] = v;
    __syncthreads();
    const float mean = (sw[g][0] + sw[g][1]) * (1.0f / 128.0f);
    const float rn = rsqrtf(mean + 1e-6f);
    const float wv = isQ ? loadf_any(qw, d, qwbf) : loadf_any(kw, d, kwbf);
    const float xn = x * rn * wv;
    sh[g][d] = xn;
    __syncthreads();
    const float other = sh[g][d ^ 64];
    const float cv = loadf_any(cosb, (size_t)s * HDIM + d, cbf);
    const float sv = loadf_any(sinb, (size_t)s * HDIM + d, sbf);
    const float o = xn * cv + (d < 64 ? -other : other) * sv;
    *ptr = f2bf(o);
  } else {
    const int r = b - 36864;
    const int s0 = (r & 31) * 64, d0 = ((r >> 5) & 1) * 64, hk = r >> 6;
#pragma unroll
    for (int i = 0; i < 16; i++) {
      const int idx = i * 256 + t;
      const int rr = idx >> 6, c = idx & 63;
      tile[rr][c] = QKV[(size_t)(s0 + rr) * 5120 + 4608 + hk * HDIM + d0 + c];
    }
    __syncthreads();
#pragma unroll
    for (int i = 0; i < 16; i++) {
      const int idx = i * 256 + t;
      const int dd = idx >> 6, ss = idx & 63;
      Vt[((size_t)hk * HDIM + d0 + dd) * SEQ + s0 + ss] = tile[ss][dd];
    }
  }
}

// ---------------------------------------------------------------------------
// Flash attention (round-6 proven binary: single K/V buffer, 2 barriers/iter,
// static-max softmax, XOR-swizzled K/V LDS, native bf16-cast P-store,
// complementary-paired block order). 80.4-80.7 us measured; dbuf refuted 3x.
// ---------------------------------------------------------------------------
__global__ __launch_bounds__(256) void flash_attn(
    const u16* __restrict__ QKV, const u16* __restrict__ Vt,
    u16* __restrict__ O) {
  __shared__ alignas(16) u16 Klds[64 * 128];   // [kv][d], chunk-swizzled
  __shared__ alignas(16) u16 Vlds[128 * 64];   // [d][kv], chunk-swizzled
  __shared__ alignas(16) u16 Plds[4][32 * 72]; // per-wave P, row stride 72
  const int t = threadIdx.x;
  const int w = t >> 6;
  const int lane = t & 63;
  const int lhi = lane >> 4, llo = lane & 15;
  const int b = blockIdx.x;
  const int bi = b & 255;
  const int qt = (b < 256) ? (15 - (bi >> 5)) : (bi >> 5);  // paired balance
  const int h = bi & 31, hk = h >> 3;
  const int q0 = qt * 128;
  const int qw0 = q0 + w * 32;
  const float scale = 0.08838834764831845f;  // 1/sqrt(128)
  const float SMAX = 16.0f;                  // static softmax reference

  bf16x8 qf[2][4];
#pragma unroll
  for (int i = 0; i < 2; i++)
#pragma unroll
    for (int c = 0; c < 4; c++)
      qf[i][c] = *(const bf16x8*)(QKV + (size_t)(qw0 + i * 16 + llo) * 5120 +
                                  h * HDIM + c * 32 + lhi * 8);

  floatx4 oacc[2][8];
  float lacc[2][4];
#pragma unroll
  for (int i = 0; i < 2; i++) {
#pragma unroll
    for (int d = 0; d < 8; d++) oacc[i][d] = (floatx4)(0.0f);
#pragma unroll
    for (int r = 0; r < 4; r++) lacc[i][r] = 0.0f;
  }

  const int ntiles = 2 * qt + 2;
  for (int tt = 0; tt < ntiles; tt++) {
    const int kv0 = tt * 64;
#pragma unroll
    for (int r = 0; r < 4; r++) {
      const int c = r * 256 + t;
      const int base = (r * 256 + w * 64) * 8;
      // K chunk (row=c>>4, s=c&15) holds global chunk s^(row&7)
      gload_lds16(QKV + (size_t)(kv0 + (c >> 4)) * 5120 + 4096 + hk * HDIM +
                      (((c & 15) ^ ((c >> 4) & 7)) * 8),
                  &Klds[base]);
      // V chunk (row=c>>3, s=c&7) holds global chunk s^(row&7)
      gload_lds16(Vt + ((size_t)hk * HDIM + (c >> 3)) * SEQ + kv0 +
                      (((c & 7) ^ ((c >> 3) & 7)) * 8),
                  &Vlds[base]);
    }
    __syncthreads();

    floatx4 sacc[2][4];
#pragma unroll
    for (int i = 0; i < 2; i++)
#pragma unroll
      for (int j = 0; j < 4; j++) sacc[i][j] = (floatx4)(0.0f);
#pragma unroll
    for (int j = 0; j < 4; j++) {
#pragma unroll
      for (int c = 0; c < 4; c++) {
        bf16x8 kf = *(const bf16x8*)&Klds[(j * 16 + llo) * 128 +
                                          (((c * 4 + lhi) ^ (llo & 7)) * 8)];
        sacc[0][j] = mfma16(qf[0][c], kf, sacc[0][j]);
        sacc[1][j] = mfma16(qf[1][c], kf, sacc[1][j]);
      }
    }
    if (kv0 + 64 > q0) {
#pragma unroll
      for (int i = 0; i < 2; i++)
#pragma unroll
        for (int j = 0; j < 4; j++) {
          const int n = kv0 + j * 16 + llo;
#pragma unroll
          for (int r = 0; r < 4; r++) {
            const int mm = qw0 + i * 16 + lhi * 4 + r;
            if (n > mm) sacc[i][j][r] = -30000.0f;
          }
        }
    }
    // static-max softmax: p = exp(s*scale - SMAX); no shuffles, no rescale
#pragma unroll
    for (int i = 0; i < 2; i++)
#pragma unroll
      for (int j = 0; j < 4; j++)
#pragma unroll
        for (int r = 0; r < 4; r++) {
          const float p = __expf(fmaf(sacc[i][j][r], scale, -SMAX));
          lacc[i][r] += p;
          *(bf16_t*)&Plds[w][(i * 16 + lhi * 4 + r) * 72 + j * 16 + llo] =
              (bf16_t)p;
        }
    // Plds is wave-private: compiler fence + lgkm drain, no s_barrier
    asm volatile("" ::: "memory");
    __builtin_amdgcn_s_waitcnt(0);
    asm volatile("" ::: "memory");
#pragma unroll
    for (int c = 0; c < 2; c++) {
      bf16x8 pf0 = *(const bf16x8*)&Plds[w][llo * 72 + c * 32 + lhi * 8];
      bf16x8 pf1 = *(const bf16x8*)&Plds[w][(16 + llo) * 72 + c * 32 + lhi * 8];
#pragma unroll
      for (int d = 0; d < 8; d++) {
        bf16x8 vf = *(const bf16x8*)&Vlds[(d * 16 + llo) * 64 +
                                          (((c * 4 + lhi) ^ (llo & 7)) * 8)];
        oacc[0][d] = mfma16(pf0, vf, oacc[0][d]);
        oacc[1][d] = mfma16(pf1, vf, oacc[1][d]);
      }
    }
    __syncthreads();
  }
  // epilogue: reduce l across the 16 llo lanes, normalize, store
#pragma unroll
  for (int i = 0; i < 2; i++)
#pragma unroll
    for (int r = 0; r < 4; r++) {
#pragma unroll
      for (int off = 1; off < 16; off <<= 1)
        lacc[i][r] += __shfl_xor(lacc[i][r], off, 64);
      const float linv = 1.0f / lacc[i][r];
      const int row = qw0 + i * 16 + lhi * 4 + r;
#pragma unroll
      for (int d = 0; d < 8; d++)
        O[(size_t)row * 4096 + h * HDIM + d * 16 + llo] =
            f2bf(oacc[i][d][r] * linv);
    }
}

// ---------------------------------------------------------------------------
extern "C" void kernel_launch(void* const* d_in, const int* in_sizes, int n_in,
                              void* d_out, int out_size, void* d_ws, size_t ws_size,
                              hipStream_t stream) {
  // Arena: 42 MB + flags (proven size). Overlays sequential-stream safe.
  char* ws = (char*)d_ws;
  u16* wqkvT  = (u16*)(ws);                   // 20 MB (5120,2048); attnO later
  u16* QKVp   = (u16*)(ws + (20ull << 20));   // 20 MB (S,5120); woT later
  u16* Vt     = (u16*)(ws + (40ull << 20));   //  2 MB (NKV,HD,S)
  int* flags  = (int*)(ws + (42ull << 20));   // 16 ints
  u16* attnO  = wqkvT;   // 16 MB, overlays wqkvT (dead after QKV GEMM)
  u16* woT    = QKVp;    // 16 MB, overlays QKVp (dead after flash)
  u16* Hb     = (u16*)d_out;  // 8 MB bf16 hidden (dead before final GEMM)

  InPack pk;
  for (int i = 0; i < 9; i++) { pk.p[i] = (const u16*)d_in[i]; pk.n[i] = in_sizes[i]; }
  detect_all<<<9, 256, 0, stream>>>(pk, flags);

  // Fused prep: convert + wq^T + wk^T + wv^T in ONE launch (vectorized).
  prep_all<<<6656, 256, 0, stream>>>(
      d_in[0], d_in[1], d_in[2], d_in[3], Hb, wqkvT, flags);

  // Fused QKV projection: (S,2048) @ (2048,5120) -> (S,5120) bf16
  gemm_bt_bf16<<<dim3(40, 16), 256, 0, stream>>>(
      Hb, wqkvT, QKVp, 2048, 5120, 2048, flags + 15);

  // Fused RMSNorm+RoPE + V transpose (one launch, was two).
  norm_rope_vt<<<37120, 256, 0, stream>>>(
      QKVp, Vt, d_in[5], d_in[6], d_in[7], d_in[8], flags);

  flash_attn<<<512, 256, 0, stream>>>(QKVp, Vt, attnO);

  transpose_any<<<dim3(32, 64), 256, 0, stream>>>(d_in[4], woT, 4096, 2048, flags + 4);
  // Output projection: within-block split-K=4 (2048x2048x4096)
  gemm_bt_splitk<<<dim3(16, 16), 1024, 0, stream>>>(
      attnO, woT, d_out, 2048, 2048, 4096, flags + 0);
}

// Round 9
// 364.950 us; speedup vs baseline: 1.1099x; 1.0572x over previous
//
#include <hip/hip_runtime.h>
#include <hip/hip_bf16.h>
#include <stdint.h>

#define SEQ 2048
#define HDIM 128
#define NHEADS 32
#define NKVH 4

typedef unsigned short u16;
typedef __bf16 bf16_t;
typedef bf16_t bf16x8 __attribute__((ext_vector_type(8)));
typedef float floatx4 __attribute__((ext_vector_type(4)));

__device__ __forceinline__ float bf2f(u16 u) {
  union { uint32_t i; float f; } v; v.i = ((uint32_t)u) << 16; return v.f;
}
__device__ __forceinline__ u16 f2bf(float f) {
  if (__builtin_isnan(f)) return 0;
  union { float f; uint32_t i; } v; v.f = f;
  uint32_t r = v.i + 0x7fffu + ((v.i >> 16) & 1u);
  return (u16)(r >> 16);
}
__device__ __forceinline__ float loadf_any(const void* p, size_t i, int isbf) {
  return isbf ? bf2f(((const u16*)p)[i]) : ((const float*)p)[i];
}

__device__ __forceinline__ void gload_lds16(const u16* g, u16* l) {
  __builtin_amdgcn_global_load_lds((__attribute__((address_space(1))) void*)g,
                                   (__attribute__((address_space(3))) void*)l,
                                   16, 0, 0);
}

__device__ __forceinline__ floatx4 mfma16(bf16x8 a, bf16x8 b, floatx4 c) {
  return __builtin_amdgcn_mfma_f32_16x16x32_bf16(a, b, c, 0, 0, 0);
}

// ---------------------------------------------------------------------------
// Fused per-tensor dtype detection: one launch, one block per input.
// flag=1 if bf16, 0 if fp32. Block 0 also sets flags[15]=1 (constant).
// ---------------------------------------------------------------------------
struct InPack { const u16* p[9]; int n[9]; };

__global__ void detect_all(InPack pk, int* __restrict__ flags) {
  const int which = blockIdx.x;
  const u16* x = pk.p[which];
  const int n = pk.n[which];
  __shared__ int s_sane, s_zeven, s_zodd;
  if (threadIdx.x == 0) { s_sane = 0; s_zeven = 0; s_zodd = 0; }
  __syncthreads();
  const int ns = n < 8192 ? n : 8192;
  int sane = 0, zeven = 0, zodd = 0;
  for (int i = threadIdx.x; i < ns; i += 256) {
    const u16 u = x[i];
    const int e = (u >> 7) & 0xff;
    if ((e >= 96 && e <= 159) || u == 0) sane++;
    if (u == 0) { if (i & 1) zodd++; else zeven++; }
  }
#pragma unroll
  for (int off = 32; off >= 1; off >>= 1) {
    sane += __shfl_xor(sane, off, 64);
    zeven += __shfl_xor(zeven, off, 64);
    zodd += __shfl_xor(zodd, off, 64);
  }
  if ((threadIdx.x & 63) == 0) {
    atomicAdd(&s_sane, sane);
    atomicAdd(&s_zeven, zeven);
    atomicAdd(&s_zodd, zodd);
  }
  __syncthreads();
  if (threadIdx.x == 0) {
    const int even = (ns + 1) / 2, odd = ns / 2;
    const bool mostly_sane = (s_sane * 10 >= ns * 9);
    const bool fp32_const_pattern = (s_zeven * 2 >= even) && (s_zodd * 10 <= odd);
    flags[which] = (mostly_sane && !fp32_const_pattern) ? 1 : 0;
    if (which == 0) flags[15] = 1;
  }
}

// ---------------------------------------------------------------------------
// Vectorized transpose tile: in (R x C, fp32|bf16) -> out (C x R, bf16).
// ---------------------------------------------------------------------------
__device__ __forceinline__ void transpose_tile(
    u16 (&tile)[64][65], const void* __restrict__ in, u16* __restrict__ out,
    int R, int C, int isbf, int bx, int by) {
  const int c0 = bx * 64, r0 = by * 64;
  const int t = threadIdx.x;
  const int tr = t >> 4;         // 0..15
  const int tc4 = (t & 15) * 4;  // 0,4,..,60
  if (isbf) {
#pragma unroll
    for (int i = 0; i < 4; i++) {
      const int r = i * 16 + tr;
      const ushort4 v = *(const ushort4*)((const u16*)in +
                                          (size_t)(r0 + r) * C + c0 + tc4);
      tile[r][tc4 + 0] = v.x; tile[r][tc4 + 1] = v.y;
      tile[r][tc4 + 2] = v.z; tile[r][tc4 + 3] = v.w;
    }
  } else {
#pragma unroll
    for (int i = 0; i < 4; i++) {
      const int r = i * 16 + tr;
      const float4 v = *(const float4*)((const float*)in +
                                        (size_t)(r0 + r) * C + c0 + tc4);
      tile[r][tc4 + 0] = f2bf(v.x); tile[r][tc4 + 1] = f2bf(v.y);
      tile[r][tc4 + 2] = f2bf(v.z); tile[r][tc4 + 3] = f2bf(v.w);
    }
  }
  __syncthreads();
#pragma unroll
  for (int j = 0; j < 4; j++) {
    const int cc = j * 16 + tr;
    ushort4 o;
    o.x = tile[tc4 + 0][cc]; o.y = tile[tc4 + 1][cc];
    o.z = tile[tc4 + 2][cc]; o.w = tile[tc4 + 3][cc];
    *(ushort4*)(out + (size_t)(c0 + cc) * R + r0 + tc4) = o;
  }
}

// ---------------------------------------------------------------------------
// Fused prep: {hidden convert, wq^T, wk^T, wv^T} and (if has_wo) wo^T too.
// Ranges: [0,2048) wq | [2048,2304) wk | [2304,2560) wv |
//         [2560, 2560+2048*has_wo) wo | rest: convert (4096 blocks).
// ---------------------------------------------------------------------------
__global__ __launch_bounds__(256) void prep_all(
    const void* __restrict__ hs, const void* __restrict__ wq,
    const void* __restrict__ wk, const void* __restrict__ wv,
    const void* __restrict__ wo,
    u16* __restrict__ Hb, u16* __restrict__ wqkvT, u16* __restrict__ woT,
    int has_wo, const int* __restrict__ flags) {
  __shared__ u16 tile[64][65];
  const int b = blockIdx.x;
  if (b < 2048) {
    transpose_tile(tile, wq, wqkvT, 2048, 4096, flags[1], b & 63, b >> 6);
  } else if (b < 2304) {
    const int r = b - 2048;
    transpose_tile(tile, wk, wqkvT + 4096ull * 2048, 2048, 512, flags[2],
                   r & 7, r >> 3);
  } else if (b < 2560) {
    const int r = b - 2304;
    transpose_tile(tile, wv, wqkvT + 4608ull * 2048, 2048, 512, flags[3],
                   r & 7, r >> 3);
  } else if (has_wo && b < 4608) {
    const int r = b - 2560;
    transpose_tile(tile, wo, woT, 4096, 2048, flags[4], r & 31, r >> 5);
  } else {
    const int r = b - (has_wo ? 4608 : 2560);
    const int base = r * 1024 + threadIdx.x * 4;
    if (flags[0]) {
      *(ushort4*)(Hb + base) = *(const ushort4*)((const u16*)hs + base);
    } else {
      const float4 v = *(const float4*)((const float*)hs + base);
      ushort4 o;
      o.x = f2bf(v.x); o.y = f2bf(v.y); o.z = f2bf(v.z); o.w = f2bf(v.w);
      *(ushort4*)(Hb + base) = o;
    }
  }
}

// ---------------------------------------------------------------------------
// dtype-aware transpose: fallback standalone launch for wo (small-ws mode).
// ---------------------------------------------------------------------------
__global__ __launch_bounds__(256) void transpose_any(
    const void* __restrict__ in, u16* __restrict__ out, int R, int C,
    const int* __restrict__ flag) {
  __shared__ u16 tile[64][65];
  transpose_tile(tile, in, out, R, C, *flag, blockIdx.x, blockIdx.y);
}

// ---------------------------------------------------------------------------
// m97-structure GEMM (128x128 tile): QKV projection (640 blocks = 2.5/CU).
// ---------------------------------------------------------------------------
__global__ __launch_bounds__(256) void gemm_bt_bf16(
    const u16* __restrict__ A, const u16* __restrict__ BT,
    void* __restrict__ C, int M, int N, int K,
    const int* __restrict__ cflag) {
  __shared__ alignas(16) u16 As[128 * 32];
  __shared__ alignas(16) u16 Bs[128 * 32];
  const int t = threadIdx.x;
  const int w = t >> 6;
  const int lane = t & 63;
  const int lhi = lane >> 4, llo = lane & 15;
  const int m0 = blockIdx.y * 128, n0 = blockIdx.x * 128;
  const int wm = (w & 1) * 64, wn = (w >> 1) * 64;

  floatx4 acc[4][4];
#pragma unroll
  for (int i = 0; i < 4; i++)
#pragma unroll
    for (int j = 0; j < 4; j++) acc[i][j] = (floatx4)(0.0f);

  for (int k0 = 0; k0 < K; k0 += 32) {
#pragma unroll
    for (int r = 0; r < 2; r++) {
      const int c = r * 256 + t;
      const int row = c >> 2, kc = c & 3;
      const int base = (r * 256 + w * 64) * 8;
      gload_lds16(A + (size_t)(m0 + row) * K + k0 + kc * 8, &As[base]);
      gload_lds16(BT + (size_t)(n0 + row) * K + k0 + kc * 8, &Bs[base]);
    }
    __syncthreads();
    bf16x8 af[4], bfr[4];
#pragma unroll
    for (int i = 0; i < 4; i++)
      af[i] = *(const bf16x8*)&As[(wm + i * 16 + llo) * 32 + lhi * 8];
#pragma unroll
    for (int j = 0; j < 4; j++)
      bfr[j] = *(const bf16x8*)&Bs[(wn + j * 16 + llo) * 32 + lhi * 8];
#pragma unroll
    for (int i = 0; i < 4; i++)
#pragma unroll
      for (int j = 0; j < 4; j++)
        acc[i][j] = mfma16(af[i], bfr[j], acc[i][j]);
    __syncthreads();
  }
  const int cbf = *cflag;
#pragma unroll
  for (int i = 0; i < 4; i++) {
    const int row0 = m0 + wm + i * 16 + lhi * 4;
#pragma unroll
    for (int j = 0; j < 4; j++) {
      const int col = n0 + wn + j * 16 + llo;
#pragma unroll
      for (int r = 0; r < 4; r++) {
        if (cbf) ((u16*)C)[(size_t)(row0 + r) * N + col] = f2bf(acc[i][j][r]);
        else ((float*)C)[(size_t)(row0 + r) * N + col] = acc[i][j][r];
      }
    }
  }
}

// ---------------------------------------------------------------------------
// Within-block split-K GEMM for small output grids (output projection).
// ---------------------------------------------------------------------------
__global__ __launch_bounds__(1024) void gemm_bt_splitk(
    const u16* __restrict__ A, const u16* __restrict__ BT,
    void* __restrict__ C, int M, int N, int K,
    const int* __restrict__ cflag) {
  __shared__ alignas(16) u16 smem[4][2][128 * 32];  // 64 KiB total
  const int t = threadIdx.x;
  const int g = t >> 8;        // k-group 0..3
  const int tg = t & 255;      // thread within group
  const int w = tg >> 6;       // wave within group 0..3
  const int lane = t & 63;
  const int lhi = lane >> 4, llo = lane & 15;
  const int m0 = blockIdx.y * 128, n0 = blockIdx.x * 128;
  const int wm = (w & 1) * 64, wn = (w >> 1) * 64;
  const int kq = K >> 2;
  const int kbeg = g * kq;
  u16* As = smem[g][0];
  u16* Bs = smem[g][1];

  floatx4 acc[4][4];
#pragma unroll
  for (int i = 0; i < 4; i++)
#pragma unroll
    for (int j = 0; j < 4; j++) acc[i][j] = (floatx4)(0.0f);

  for (int k0 = 0; k0 < kq; k0 += 32) {
#pragma unroll
    for (int r = 0; r < 2; r++) {
      const int c = r * 256 + tg;
      const int row = c >> 2, kc = c & 3;
      const int base = (r * 256 + w * 64) * 8;  // wave-uniform LDS dest
      gload_lds16(A + (size_t)(m0 + row) * K + kbeg + k0 + kc * 8, &As[base]);
      gload_lds16(BT + (size_t)(n0 + row) * K + kbeg + k0 + kc * 8, &Bs[base]);
    }
    __syncthreads();
    bf16x8 af[4], bfr[4];
#pragma unroll
    for (int i = 0; i < 4; i++)
      af[i] = *(const bf16x8*)&As[(wm + i * 16 + llo) * 32 + lhi * 8];
#pragma unroll
    for (int j = 0; j < 4; j++)
      bfr[j] = *(const bf16x8*)&Bs[(wn + j * 16 + llo) * 32 + lhi * 8];
#pragma unroll
    for (int i = 0; i < 4; i++)
#pragma unroll
      for (int j = 0; j < 4; j++)
        acc[i][j] = mfma16(af[i], bfr[j], acc[i][j]);
    __syncthreads();
  }

  // cross-group reduce: reuse staging LDS as 128x128 f32 (exactly 64 KiB).
  float* red = (float*)&smem[0][0][0];
  for (int gg = 0; gg < 4; gg++) {
    if (g == gg) {
#pragma unroll
      for (int i = 0; i < 4; i++)
#pragma unroll
        for (int j = 0; j < 4; j++) {
          const int col = wn + j * 16 + llo;
#pragma unroll
          for (int r = 0; r < 4; r++) {
            const int row = wm + i * 16 + lhi * 4 + r;
            if (gg == 0) red[row * 128 + col] = acc[i][j][r];
            else red[row * 128 + col] += acc[i][j][r];
          }
        }
    }
    __syncthreads();
  }
  const int cbf = *cflag;
#pragma unroll
  for (int i = 0; i < 16; i++) {
    const int idx = i * 1024 + t;           // 16384 = 128*128
    const int rr = idx >> 7, cc = idx & 127;
    const float v = red[rr * 128 + cc];
    if (cbf) ((u16*)C)[(size_t)(m0 + rr) * N + n0 + cc] = f2bf(v);
    else ((float*)C)[(size_t)(m0 + rr) * N + n0 + cc] = v;
  }
}

// ---------------------------------------------------------------------------
// Fused RMSNorm+RoPE (Q/K cols) + V transpose in ONE launch.
// ---------------------------------------------------------------------------
__global__ __launch_bounds__(256) void norm_rope_vt(
    u16* __restrict__ QKV, u16* __restrict__ Vt,
    const void* __restrict__ qw, const void* __restrict__ kw,
    const void* __restrict__ cosb, const void* __restrict__ sinb,
    const int* __restrict__ flags) {
  __shared__ float sw[2][2];
  __shared__ float sh[2][128];
  __shared__ u16 tile[64][65];
  const int b = blockIdx.x;
  const int t = threadIdx.x;
  if (b < 36864) {
    const int qwbf = flags[5], kwbf = flags[6], cbf = flags[7], sbf = flags[8];
    const int s = b / 18, hp = b - s * 18;
    const int g = t >> 7, d = t & 127;
    const int hy = hp * 2 + g;
    const bool isQ = hy < NHEADS;
    const int col = isQ ? hy * HDIM : 4096 + (hy - NHEADS) * HDIM;
    u16* ptr = QKV + (size_t)s * 5120 + col + d;
    const float x = bf2f(*ptr);
    float v = x * x;
#pragma unroll
    for (int off = 32; off >= 1; off >>= 1) v += __shfl_xor(v, off, 64);
    if ((d & 63) == 0) sw[g][d >> 6] = v;
    __syncthreads();
    const float mean = (sw[g][0] + sw[g][1]) * (1.0f / 128.0f);
    const float rn = rsqrtf(mean + 1e-6f);
    const float wv = isQ ? loadf_any(qw, d, qwbf) : loadf_any(kw, d, kwbf);
    const float xn = x * rn * wv;
    sh[g][d] = xn;
    __syncthreads();
    const float other = sh[g][d ^ 64];
    const float cv = loadf_any(cosb, (size_t)s * HDIM + d, cbf);
    const float sv = loadf_any(sinb, (size_t)s * HDIM + d, sbf);
    const float o = xn * cv + (d < 64 ? -other : other) * sv;
    *ptr = f2bf(o);
  } else {
    const int r = b - 36864;
    const int s0 = (r & 31) * 64, d0 = ((r >> 5) & 1) * 64, hk = r >> 6;
#pragma unroll
    for (int i = 0; i < 16; i++) {
      const int idx = i * 256 + t;
      const int rr = idx >> 6, c = idx & 63;
      tile[rr][c] = QKV[(size_t)(s0 + rr) * 5120 + 4608 + hk * HDIM + d0 + c];
    }
    __syncthreads();
#pragma unroll
    for (int i = 0; i < 16; i++) {
      const int idx = i * 256 + t;
      const int dd = idx >> 6, ss = idx & 63;
      Vt[((size_t)hk * HDIM + d0 + dd) * SEQ + s0 + ss] = tile[ss][dd];
    }
  }
}

// ---------------------------------------------------------------------------
// Flash attention v4: QBLK=64 for 4-blocks/CU residency (m114: wave-level
// TLP across blocks is what hides the barrier drain — dbuf refuted 3x).
// Grid 1024 = (qt 0..31, head); wave owns 16 q-rows; K/V staging and
// swizzles byte-identical to the proven kernel; P half-split stride 40.
// LDS = 16K (K) + 16K (V) + 5K (P) = 37888 B -> 4 blocks/CU.
// Complementary 4-way qt map: co-resident quads sum to 66 iters.
// Static-max softmax is ADDITIVE across kv tiles (fixed SMAX), semantics
// unchanged. Mid-softmax s_waitcnt(0) harmless: vmcnt==0 there (single buf).
// ---------------------------------------------------------------------------
__global__ __launch_bounds__(256) void flash_attn(
    const u16* __restrict__ QKV, const u16* __restrict__ Vt,
    u16* __restrict__ O) {
  __shared__ alignas(16) u16 Klds[64 * 128];   // [kv][d], chunk-swizzled
  __shared__ alignas(16) u16 Vlds[128 * 64];   // [d][kv], chunk-swizzled
  __shared__ alignas(16) u16 Plds[4][16 * 40]; // per-wave P half, stride 40
  const int t = threadIdx.x;
  const int w = t >> 6;
  const int lane = t & 63;
  const int lhi = lane >> 4, llo = lane & 15;
  const int b = blockIdx.x;
  const int bi = b & 255;
  const int kq = bi >> 5;  // 0..7
  int qt;
  if (b < 256) qt = 31 - kq;
  else if (b < 512) qt = kq;
  else if (b < 768) qt = 23 - kq;
  else qt = 8 + kq;
  const int h = bi & 31, hk = h >> 3;
  const int q0 = qt * 64;
  const int qw0 = q0 + w * 16;
  const float scale = 0.08838834764831845f;  // 1/sqrt(128)
  const float SMAX = 16.0f;                  // static softmax reference

  bf16x8 qf[4];
#pragma unroll
  for (int c = 0; c < 4; c++)
    qf[c] = *(const bf16x8*)(QKV + (size_t)(qw0 + llo) * 5120 +
                             h * HDIM + c * 32 + lhi * 8);

  floatx4 oacc[8];
  float lacc[4];
#pragma unroll
  for (int d = 0; d < 8; d++) oacc[d] = (floatx4)(0.0f);
#pragma unroll
  for (int r = 0; r < 4; r++) lacc[r] = 0.0f;

  const int ntiles = qt + 1;
  for (int tt = 0; tt < ntiles; tt++) {
    const int kv0 = tt * 64;
#pragma unroll
    for (int r = 0; r < 4; r++) {
      const int c = r * 256 + t;
      const int base = (r * 256 + w * 64) * 8;
      // K chunk (row=c>>4, s=c&15) holds global chunk s^(row&7)
      gload_lds16(QKV + (size_t)(kv0 + (c >> 4)) * 5120 + 4096 + hk * HDIM +
                      (((c & 15) ^ ((c >> 4) & 7)) * 8),
                  &Klds[base]);
      // V chunk (row=c>>3, s=c&7) holds global chunk s^(row&7)
      gload_lds16(Vt + ((size_t)hk * HDIM + (c >> 3)) * SEQ + kv0 +
                      (((c & 7) ^ ((c >> 3) & 7)) * 8),
                  &Vlds[base]);
    }
    __syncthreads();

    floatx4 sacc[4];
#pragma unroll
    for (int j = 0; j < 4; j++) sacc[j] = (floatx4)(0.0f);
#pragma unroll
    for (int j = 0; j < 4; j++) {
#pragma unroll
      for (int c = 0; c < 4; c++) {
        bf16x8 kf = *(const bf16x8*)&Klds[(j * 16 + llo) * 128 +
                                          (((c * 4 + lhi) ^ (llo & 7)) * 8)];
        sacc[j] = mfma16(qf[c], kf, sacc[j]);
      }
    }
    if (kv0 + 64 > q0) {  // only the diagonal tile
#pragma unroll
      for (int j = 0; j < 4; j++) {
        const int n = kv0 + j * 16 + llo;
#pragma unroll
        for (int r = 0; r < 4; r++) {
          const int mm = qw0 + lhi * 4 + r;
          if (n > mm) sacc[j][r] = -30000.0f;
        }
      }
    }
    // static-max softmax in two kv-32 halves sharing the P buffer.
#pragma unroll
    for (int hh = 0; hh < 2; hh++) {
#pragma unroll
      for (int jj = 0; jj < 2; jj++) {
        const int j = hh * 2 + jj;
#pragma unroll
        for (int r = 0; r < 4; r++) {
          const float p = __expf(fmaf(sacc[j][r], scale, -SMAX));
          lacc[r] += p;
          *(bf16_t*)&Plds[w][(lhi * 4 + r) * 40 + jj * 16 + llo] = (bf16_t)p;
        }
      }
      // Plds wave-private; vmcnt already 0 here (single-buffer)
      asm volatile("" ::: "memory");
      __builtin_amdgcn_s_waitcnt(0);
      asm volatile("" ::: "memory");
      bf16x8 pf = *(const bf16x8*)&Plds[w][llo * 40 + lhi * 8];
#pragma unroll
      for (int d = 0; d < 8; d++) {
        bf16x8 vf = *(const bf16x8*)&Vlds[(d * 16 + llo) * 64 +
                                          (((hh * 4 + lhi) ^ (llo & 7)) * 8)];
        oacc[d] = mfma16(pf, vf, oacc[d]);
      }
    }
    __syncthreads();
  }
  // epilogue: reduce l across the 16 llo lanes, normalize, store
#pragma unroll
  for (int r = 0; r < 4; r++) {
#pragma unroll
    for (int off = 1; off < 16; off <<= 1)
      lacc[r] += __shfl_xor(lacc[r], off, 64);
    const float linv = 1.0f / lacc[r];
    const int row = qw0 + lhi * 4 + r;
#pragma unroll
    for (int d = 0; d < 8; d++)
      O[(size_t)row * 4096 + h * HDIM + d * 16 + llo] =
          f2bf(oacc[d][r] * linv);
  }
}

// ---------------------------------------------------------------------------
extern "C" void kernel_launch(void* const* d_in, const int* in_sizes, int n_in,
                              void* d_out, int out_size, void* d_ws, size_t ws_size,
                              hipStream_t stream) {
  // Arena: 42 MB + flags; optional +16 MB woT region if workspace allows.
  char* ws = (char*)d_ws;
  u16* wqkvT  = (u16*)(ws);                   // 20 MB (5120,2048); attnO later
  u16* QKVp   = (u16*)(ws + (20ull << 20));   // 20 MB (S,5120); woT fallback
  u16* Vt     = (u16*)(ws + (40ull << 20));   //  2 MB (NKV,HD,S)
  int* flags  = (int*)(ws + (42ull << 20));   // 16 ints
  u16* attnO  = wqkvT;   // 16 MB, overlays wqkvT (dead after QKV GEMM)
  u16* Hb     = (u16*)d_out;  // 8 MB bf16 hidden (dead before final GEMM)

  const bool bigws = ws_size >= (61ull << 20);
  u16* woT = bigws ? (u16*)(ws + (44ull << 20))  // dedicated 16 MB region
                   : QKVp;                       // overlay (post-flash only)

  InPack pk;
  for (int i = 0; i < 9; i++) { pk.p[i] = (const u16*)d_in[i]; pk.n[i] = in_sizes[i]; }
  detect_all<<<9, 256, 0, stream>>>(pk, flags);

  // Fused prep: convert + wq^T + wk^T + wv^T (+ wo^T if bigws) in ONE launch.
  prep_all<<<bigws ? 8704 : 6656, 256, 0, stream>>>(
      d_in[0], d_in[1], d_in[2], d_in[3], d_in[4], Hb, wqkvT, woT,
      bigws ? 1 : 0, flags);

  // Fused QKV projection: (S,2048) @ (2048,5120) -> (S,5120) bf16
  gemm_bt_bf16<<<dim3(40, 16), 256, 0, stream>>>(
      Hb, wqkvT, QKVp, 2048, 5120, 2048, flags + 15);

  // Fused RMSNorm+RoPE + V transpose (one launch).
  norm_rope_vt<<<37120, 256, 0, stream>>>(
      QKVp, Vt, d_in[5], d_in[6], d_in[7], d_in[8], flags);

  flash_attn<<<1024, 256, 0, stream>>>(QKVp, Vt, attnO);

  if (!bigws)
    transpose_any<<<dim3(32, 64), 256, 0, stream>>>(d_in[4], woT, 4096, 2048,
                                                    flags + 4);
  // Output projection: within-block split-K=4 (2048x2048x4096)
  gemm_bt_splitk<<<dim3(16, 16), 1024, 0, stream>>>(
      attnO, woT, d_out, 2048, 2048, 4096, flags + 0);
}